// Round 4
// baseline (787.557 us; speedup 1.0000x reference)
//
#include <hip/hip_runtime.h>
#include <math.h>

// ============================================================================
// R4 = DECISIVE MEASUREMENT ROUND (kernel body identical to R3's best, 683 us).
// The kernel is launched TWICE (idempotent: pure function of x, deterministic,
// rewrites identical output). dur_us(R4) - 683 = T_kernel + ~15us launch gap.
//   - If dur ~ 980-1010: kernel is ~300us, read-pinned -> keep optimizing reads.
//   - If dur ~ 795-830:  kernel is ~100-130us, near the 512MiB fetch floor ->
//                        harness fixtures (335us ws-poison fill + tiny-memset
//                        gaps) dominate dur_us; revert to single launch and
//                        declare roofline.
// Four read-pattern variants (stride-2, unit-stride, rotated, grid-strided,
// NT) all measured within +-2%: this round disambiguates WHY.
// ============================================================================

constexpr int HWPIX = 4096;   // 64*64 pixels per image
constexpr int BLK   = 256;

typedef float v4f __attribute__((ext_vector_type(4)));

__global__ __launch_bounds__(BLK) void oracle_kernel(
    const float* __restrict__ x,
    const float* __restrict__ opp_start,
    float* __restrict__ out)
{
    const int b    = blockIdx.x;
    const int t    = threadIdx.x;
    const int lane = t & 63;
    const int wv   = t >> 6;   // wave id 0..3

    // x for this image viewed as 8192 contiguous float4 entries;
    // entry 2p   = pixel p channels 0..3 (ch1=[1] food, ch3=[3] opp)
    // entry 2p+1 = pixel p channels 4..7 (never needed)
    const v4f* xb = (const v4f*)(x + (size_t)b * HWPIX * 8);

    __shared__ unsigned char s_food[HWPIX];  // 4 KiB byte mask
    __shared__ int   s_stat[4][3];           // per-wave: food_cnt, opp_cnt, first_opp
    __shared__ float s_m1[4], s_m2[4];
    __shared__ int   s_i1[4];
    __shared__ int   s_hdr[3];               // n_food, n_opp, first_opp
    __shared__ int   s_dec[3];               // ambiguous, pick_nearest, min_idx

    // ---- Phase 1: UNIT-STRIDE stream of all of x, NON-TEMPORAL ---------
    // NT kept from R3 (-14us, and it makes run1/run2 symmetric: no LLC
    // allocation, so the second launch re-reads from HBM exactly like the
    // first -> dur delta == one full kernel pass).
    const bool even  = (t & 1) == 0;
    const int  pbase = t >> 1;               // pixel owned by even thread at j=0
    int fc = 0, oc = 0, fo = HWPIX;

    #pragma unroll
    for (int jo = 0; jo < 32; jo += 8) {
        v4f v[8];
        #pragma unroll
        for (int ji = 0; ji < 8; ++ji)
            v[ji] = __builtin_nontemporal_load(&xb[t + BLK * (jo + ji)]);
        #pragma unroll
        for (int ji = 0; ji < 8; ++ji) {
            const int  p    = pbase + 128 * (jo + ji);
            const bool food = (v[ji][1] == 1.0f);
            const bool opp  = (v[ji][3] == 1.0f);
            if (even) {
                s_food[p] = food ? 1 : 0;
                fc += food ? 1 : 0;
                oc += opp  ? 1 : 0;
                fo  = opp ? min(fo, p) : fo;
            }
        }
    }

    // ---- block reduction of counts / first-opp (odd threads contribute 0)
    #pragma unroll
    for (int off = 32; off > 0; off >>= 1) {
        fc += __shfl_down(fc, off);
        oc += __shfl_down(oc, off);
        fo  = min(fo, __shfl_down(fo, off));
    }
    if (lane == 0) { s_stat[wv][0] = fc; s_stat[wv][1] = oc; s_stat[wv][2] = fo; }
    __syncthreads();                          // also publishes s_food
    if (t == 0) {
        int nf = 0, no = 0, f = HWPIX;
        for (int w = 0; w < 4; ++w) {
            nf += s_stat[w][0]; no += s_stat[w][1]; f = min(f, s_stat[w][2]);
        }
        if (f == HWPIX) f = 0;                // argmax of all-False == 0
        s_hdr[0] = nf; s_hdr[1] = no; s_hdr[2] = f;
    }
    __syncthreads();
    const int n_food    = s_hdr[0];
    const int n_opp     = s_hdr[1];
    const int first_opp = s_hdr[2];
    const float orow = (float)(first_opp >> 6);
    const float ocol = (float)(first_opp & 63);

    // ---- Phase 2: two smallest food distances, first-argmin tiebreak ----
    float m1 = INFINITY, m2 = INFINITY;
    int   i1 = 0x7fffffff;
    #pragma unroll
    for (int k = 0; k < 16; ++k) {
        const int p = t + BLK * k;
        if (s_food[p]) {
            const float dr = (float)(p >> 6) - orow;
            const float dc = (float)(p & 63) - ocol;
            const float d  = sqrtf(dr * dr + dc * dc); // exact int squares; IEEE sqrt == numpy
            if (d < m1)      { m2 = m1; m1 = d; i1 = p; }
            else if (d < m2) { m2 = d; }               // d == m1 duplicate -> min2
        }
    }
    #pragma unroll
    for (int off = 32; off > 0; off >>= 1) {
        const float n1 = __shfl_down(m1, off);
        const int   j1 = __shfl_down(i1, off);
        const float n2 = __shfl_down(m2, off);
        if (n1 < m1 || (n1 == m1 && j1 < i1)) {
            m2 = fminf(m1, n2); m1 = n1; i1 = j1;
        } else {
            m2 = fminf(m2, n1);
        }
    }
    if (lane == 0) { s_m1[wv] = m1; s_m2[wv] = m2; s_i1[wv] = i1; }
    __syncthreads();

    // ---- decision on thread 0 ------------------------------------------
    if (t == 0) {
        m1 = s_m1[0]; m2 = s_m2[0]; i1 = s_i1[0];
        for (int w = 1; w < 4; ++w) {
            const float n1 = s_m1[w], n2 = s_m2[w];
            const int   j1 = s_i1[w];
            if (n1 < m1 || (n1 == m1 && j1 < i1)) {
                m2 = fminf(m1, n2); m1 = n1; i1 = j1;
            } else {
                m2 = fminf(m2, n1);
            }
        }
        const float diff = m2 - m1;  // only consumed when n_food > 1 (finite)
        const bool matches_start = (orow == opp_start[0]) && (ocol == opp_start[1]);
        const bool branchA   = (n_food > 1) && (n_opp > 0) && !matches_start;
        const bool ambiguous = (branchA && (diff < 0.1f)) || ((n_food > 1) && !branchA);
        const bool pick      = (branchA && (diff >= 0.1f)) || (n_food == 1);
        s_dec[0] = ambiguous ? 1 : 0;
        s_dec[1] = pick ? 1 : 0;
        s_dec[2] = i1;
    }
    __syncthreads();

    // ---- Phase 3: broadcast write, unit-stride float4 stores ------------
    const int amb = s_dec[0], pick = s_dec[1], midx = s_dec[2];
    const unsigned* s_food32 = (const unsigned*)s_food;
    float4* ob4 = (float4*)(out + (size_t)b * HWPIX);
    #pragma unroll
    for (int k = 0; k < 4; ++k) {
        const int q = t + BLK * k;            // float4 index: pixels 4q..4q+3
        const unsigned fm = s_food32[q];      // 4 food bytes
        float4 r;
        float* rp = &r.x;
        #pragma unroll
        for (int i = 0; i < 4; ++i) {
            const int p = 4 * q + i;
            const bool f = (fm >> (8 * i)) & 0xFF;
            const float hit = amb ? (f ? 1.0f : 0.0f)
                                  : (pick ? ((p == midx) ? 1.0f : 0.0f) : 0.0f);
            rp[i] = -10.0f + 20.0f * hit;
        }
        ob4[q] = r;
    }
}

extern "C" void kernel_launch(void* const* d_in, const int* in_sizes, int n_in,
                              void* d_out, int out_size, void* d_ws, size_t ws_size,
                              hipStream_t stream) {
    const float* x         = (const float*)d_in[0];
    const float* opp_start = (const float*)d_in[1];
    float* out = (float*)d_out;
    const int B = in_sizes[0] / (HWPIX * 8);
    // PROBE: two identical, idempotent launches. dur_us - 683 isolates
    // T_kernel + one launch gap. See header comment for the decision rule.
    oracle_kernel<<<B, BLK, 0, stream>>>(x, opp_start, out);
    oracle_kernel<<<B, BLK, 0, stream>>>(x, opp_start, out);
}

// Round 5
// 680.326 us; speedup vs baseline: 1.1576x; 1.1576x over previous
//
#include <hip/hip_runtime.h>
#include <math.h>

// ============================================================================
// FINAL (reverted from R4's double-launch probe; kernel body = R3's best).
// Roofline evidence from the R4 probe: dur(double) - dur(single) =
// 787.6 - 683.0 = 104.6 us = T_kernel + ~10us launch gap -> T_kernel ~ 95 us.
// Mandatory traffic: 512 MiB read of x (every 64B sector holds needed
// ch1/ch3 bytes -> irreducible) + 64 MiB write of out = 604 MB.
// 604 MB / 95 us = 6.3 TB/s = the measured achievable HBM ceiling (the
// harness fills in the same trace sustain 6.25-6.51 TB/s).
// Remaining dur_us (~585 us) is harness fixtures: 335 us ws-poison fill +
// out-poison + ~240 us of tiny reset() memsets/launch gaps -- not
// addressable from kernel_launch.
// ============================================================================

constexpr int HWPIX = 4096;   // 64*64 pixels per image
constexpr int BLK   = 256;

typedef float v4f __attribute__((ext_vector_type(4)));

__global__ __launch_bounds__(BLK) void oracle_kernel(
    const float* __restrict__ x,
    const float* __restrict__ opp_start,
    float* __restrict__ out)
{
    const int b    = blockIdx.x;
    const int t    = threadIdx.x;
    const int lane = t & 63;
    const int wv   = t >> 6;   // wave id 0..3

    // x for this image viewed as 8192 contiguous float4 entries;
    // entry 2p   = pixel p channels 0..3 (ch1=[1] food, ch3=[3] opp)
    // entry 2p+1 = pixel p channels 4..7 (never needed)
    const v4f* xb = (const v4f*)(x + (size_t)b * HWPIX * 8);

    __shared__ unsigned char s_food[HWPIX];  // 4 KiB byte mask
    __shared__ int   s_stat[4][3];           // per-wave: food_cnt, opp_cnt, first_opp
    __shared__ float s_m1[4], s_m2[4];
    __shared__ int   s_i1[4];
    __shared__ int   s_hdr[3];               // n_food, n_opp, first_opp
    __shared__ int   s_dec[3];               // ambiguous, pick_nearest, min_idx

    // ---- Phase 1: UNIT-STRIDE stream of all of x, NON-TEMPORAL ---------
    // NT loads: x has zero reuse (512 MiB > LLC, read once), and skipping
    // LLC allocation avoids evicting the dirty poison-fill lines on the
    // read path (-14 us measured, R3 vs R1).
    const bool even  = (t & 1) == 0;
    const int  pbase = t >> 1;               // pixel owned by even thread at j=0
    int fc = 0, oc = 0, fo = HWPIX;

    #pragma unroll
    for (int jo = 0; jo < 32; jo += 8) {
        v4f v[8];
        #pragma unroll
        for (int ji = 0; ji < 8; ++ji)
            v[ji] = __builtin_nontemporal_load(&xb[t + BLK * (jo + ji)]);
        #pragma unroll
        for (int ji = 0; ji < 8; ++ji) {
            const int  p    = pbase + 128 * (jo + ji);
            const bool food = (v[ji][1] == 1.0f);
            const bool opp  = (v[ji][3] == 1.0f);
            if (even) {
                s_food[p] = food ? 1 : 0;
                fc += food ? 1 : 0;
                oc += opp  ? 1 : 0;
                fo  = opp ? min(fo, p) : fo;
            }
        }
    }

    // ---- block reduction of counts / first-opp (odd threads contribute 0)
    #pragma unroll
    for (int off = 32; off > 0; off >>= 1) {
        fc += __shfl_down(fc, off);
        oc += __shfl_down(oc, off);
        fo  = min(fo, __shfl_down(fo, off));
    }
    if (lane == 0) { s_stat[wv][0] = fc; s_stat[wv][1] = oc; s_stat[wv][2] = fo; }
    __syncthreads();                          // also publishes s_food
    if (t == 0) {
        int nf = 0, no = 0, f = HWPIX;
        for (int w = 0; w < 4; ++w) {
            nf += s_stat[w][0]; no += s_stat[w][1]; f = min(f, s_stat[w][2]);
        }
        if (f == HWPIX) f = 0;                // argmax of all-False == 0
        s_hdr[0] = nf; s_hdr[1] = no; s_hdr[2] = f;
    }
    __syncthreads();
    const int n_food    = s_hdr[0];
    const int n_opp     = s_hdr[1];
    const int first_opp = s_hdr[2];
    const float orow = (float)(first_opp >> 6);
    const float ocol = (float)(first_opp & 63);

    // ---- Phase 2: two smallest food distances, first-argmin tiebreak ----
    float m1 = INFINITY, m2 = INFINITY;
    int   i1 = 0x7fffffff;
    #pragma unroll
    for (int k = 0; k < 16; ++k) {
        const int p = t + BLK * k;
        if (s_food[p]) {
            const float dr = (float)(p >> 6) - orow;
            const float dc = (float)(p & 63) - ocol;
            const float d  = sqrtf(dr * dr + dc * dc); // exact int squares; IEEE sqrt == numpy
            if (d < m1)      { m2 = m1; m1 = d; i1 = p; }
            else if (d < m2) { m2 = d; }               // d == m1 duplicate -> min2
        }
    }
    #pragma unroll
    for (int off = 32; off > 0; off >>= 1) {
        const float n1 = __shfl_down(m1, off);
        const int   j1 = __shfl_down(i1, off);
        const float n2 = __shfl_down(m2, off);
        if (n1 < m1 || (n1 == m1 && j1 < i1)) {
            m2 = fminf(m1, n2); m1 = n1; i1 = j1;
        } else {
            m2 = fminf(m2, n1);
        }
    }
    if (lane == 0) { s_m1[wv] = m1; s_m2[wv] = m2; s_i1[wv] = i1; }
    __syncthreads();

    // ---- decision on thread 0 ------------------------------------------
    if (t == 0) {
        m1 = s_m1[0]; m2 = s_m2[0]; i1 = s_i1[0];
        for (int w = 1; w < 4; ++w) {
            const float n1 = s_m1[w], n2 = s_m2[w];
            const int   j1 = s_i1[w];
            if (n1 < m1 || (n1 == m1 && j1 < i1)) {
                m2 = fminf(m1, n2); m1 = n1; i1 = j1;
            } else {
                m2 = fminf(m2, n1);
            }
        }
        const float diff = m2 - m1;  // only consumed when n_food > 1 (finite)
        const bool matches_start = (orow == opp_start[0]) && (ocol == opp_start[1]);
        const bool branchA   = (n_food > 1) && (n_opp > 0) && !matches_start;
        const bool ambiguous = (branchA && (diff < 0.1f)) || ((n_food > 1) && !branchA);
        const bool pick      = (branchA && (diff >= 0.1f)) || (n_food == 1);
        s_dec[0] = ambiguous ? 1 : 0;
        s_dec[1] = pick ? 1 : 0;
        s_dec[2] = i1;
    }
    __syncthreads();

    // ---- Phase 3: broadcast write, unit-stride float4 stores ------------
    const int amb = s_dec[0], pick = s_dec[1], midx = s_dec[2];
    const unsigned* s_food32 = (const unsigned*)s_food;
    float4* ob4 = (float4*)(out + (size_t)b * HWPIX);
    #pragma unroll
    for (int k = 0; k < 4; ++k) {
        const int q = t + BLK * k;            // float4 index: pixels 4q..4q+3
        const unsigned fm = s_food32[q];      // 4 food bytes
        float4 r;
        float* rp = &r.x;
        #pragma unroll
        for (int i = 0; i < 4; ++i) {
            const int p = 4 * q + i;
            const bool f = (fm >> (8 * i)) & 0xFF;
            const float hit = amb ? (f ? 1.0f : 0.0f)
                                  : (pick ? ((p == midx) ? 1.0f : 0.0f) : 0.0f);
            rp[i] = -10.0f + 20.0f * hit;
        }
        ob4[q] = r;
    }
}

extern "C" void kernel_launch(void* const* d_in, const int* in_sizes, int n_in,
                              void* d_out, int out_size, void* d_ws, size_t ws_size,
                              hipStream_t stream) {
    const float* x         = (const float*)d_in[0];
    const float* opp_start = (const float*)d_in[1];
    float* out = (float*)d_out;
    const int B = in_sizes[0] / (HWPIX * 8);
    oracle_kernel<<<B, BLK, 0, stream>>>(x, opp_start, out);
}